// Round 1
// baseline (568.485 us; speedup 1.0000x reference)
//
#include <hip/hip_runtime.h>
#include <hip/hip_bf16.h>

#define NEG_SLOPE 0.2f
#define EPS 1e-16f

// ---------------------------------------------------------------- CSR build
__global__ void hist_k(const int* __restrict__ dst, int E, int* __restrict__ deg) {
    int e = blockIdx.x * blockDim.x + threadIdx.x;
    if (e < E) atomicAdd(&deg[dst[e]], 1);
}

__global__ __launch_bounds__(1024) void scan1_k(const int* __restrict__ deg, int* __restrict__ offs,
                                                int* __restrict__ bsum, int n) {
    __shared__ int tmp[1024];
    int t = threadIdx.x;
    int i = blockIdx.x * 1024 + t;
    int v = (i < n) ? deg[i] : 0;
    tmp[t] = v;
    __syncthreads();
    int run = v;
    for (int off = 1; off < 1024; off <<= 1) {
        int add = (t >= off) ? tmp[t - off] : 0;
        __syncthreads();
        run += add;
        tmp[t] = run;
        __syncthreads();
    }
    if (i < n) offs[i] = run - v;   // exclusive within block
    if (t == 1023) bsum[blockIdx.x] = run;
}

__global__ void scan2_k(int* bsum, int nb) {
    if (blockIdx.x == 0 && threadIdx.x == 0) {
        int acc = 0;
        for (int i = 0; i < nb; i++) { int v = bsum[i]; bsum[i] = acc; acc += v; }
    }
}

__global__ __launch_bounds__(1024) void scan3_k(int* __restrict__ offs, const int* __restrict__ bsum,
                                                int n, int total) {
    int i = blockIdx.x * 1024 + threadIdx.x;
    if (i < n) offs[i] += bsum[blockIdx.x];
    if (i == 0) offs[n] = total;
}

__global__ void fill_k(const int* __restrict__ src, const int* __restrict__ dst, int E,
                       const int* __restrict__ offs, int* __restrict__ cur, int* __restrict__ csr) {
    int e = blockIdx.x * blockDim.x + threadIdx.x;
    if (e >= E) return;
    int d = dst[e];
    int pos = offs[d] + atomicAdd(&cur[d], 1);
    csr[pos] = src[e];
}

// ------------------------------------------------- GEMM1: [N,128]x[128,256]
// Fused epilogue: per-head attention dots (each wave = one head's 64 cols).
__global__ __launch_bounds__(256) void gemm1_k(const float* __restrict__ x, const float* __restrict__ W1,
                                               const float* __restrict__ attS, const float* __restrict__ attD,
                                               float* __restrict__ h1, float* __restrict__ a_s,
                                               float* __restrict__ a_d, int N) {
    __shared__ float xs[16][128];
    int m0 = blockIdx.x * 16;
    int t = threadIdx.x;
    int rows = N - m0; if (rows > 16) rows = 16;

    if (rows == 16) {
        const float4* xv = (const float4*)(x + (size_t)m0 * 128);
        float4* xsv = (float4*)(&xs[0][0]);
        xsv[t] = xv[t];
        xsv[t + 256] = xv[t + 256];
    } else {
        for (int i = t; i < rows * 128; i += 256) xs[i >> 7][i & 127] = x[(size_t)m0 * 128 + i];
    }
    __syncthreads();

    float acc[16];
#pragma unroll
    for (int m = 0; m < 16; m++) acc[m] = 0.f;
    for (int k = 0; k < 128; k++) {
        float w = W1[k * 256 + t];
#pragma unroll
        for (int m = 0; m < 16; m++) acc[m] = fmaf(xs[m][k], w, acc[m]);
    }

    int lane = t & 63;
    int head = t >> 6;
    float asv = attS[t], adv = attD[t];  // attS flat [4*64], index head*64+lane == t
    for (int m = 0; m < rows; m++) {
        h1[(size_t)(m0 + m) * 256 + t] = acc[m];
        float ps = acc[m] * asv, pd = acc[m] * adv;
#pragma unroll
        for (int off = 32; off >= 1; off >>= 1) {
            ps += __shfl_xor(ps, off);
            pd += __shfl_xor(pd, off);
        }
        if (lane == 0) {
            a_s[(size_t)(m0 + m) * 4 + head] = ps;
            a_d[(size_t)(m0 + m) * 4 + head] = pd;
        }
    }
}

// ------------------------------------------------- GEMM2: [N,256]x[256,64]
__global__ __launch_bounds__(256) void gemm2_k(const float* __restrict__ h1e, const float* __restrict__ W2,
                                               const float* __restrict__ attS, const float* __restrict__ attD,
                                               float* __restrict__ h2, float* __restrict__ a_s,
                                               float* __restrict__ a_d, int N) {
    __shared__ float xs[16][256];
    int m0 = blockIdx.x * 16;
    int t = threadIdx.x;
    int rows = N - m0; if (rows > 16) rows = 16;

    if (rows == 16) {
        const float4* xv = (const float4*)(h1e + (size_t)m0 * 256);
        float4* xsv = (float4*)(&xs[0][0]);
#pragma unroll
        for (int i = 0; i < 4; i++) xsv[t + 256 * i] = xv[t + 256 * i];
    } else {
        for (int i = t; i < rows * 256; i += 256) xs[i >> 8][i & 255] = h1e[(size_t)m0 * 256 + i];
    }
    __syncthreads();

    int col = t & 63, mg = t >> 6;   // wave-uniform mg
    float acc[4] = {0.f, 0.f, 0.f, 0.f};
    for (int k = 0; k < 256; k++) {
        float w = W2[k * 64 + col];
#pragma unroll
        for (int mm = 0; mm < 4; mm++) acc[mm] = fmaf(xs[mg + 4 * mm][k], w, acc[mm]);
    }
    float asv = attS[col], adv = attD[col];
#pragma unroll
    for (int mm = 0; mm < 4; mm++) {
        int m = mg + 4 * mm;
        if (m < rows) {
            h2[(size_t)(m0 + m) * 64 + col] = acc[mm];
            float ps = acc[mm] * asv, pd = acc[mm] * adv;
#pragma unroll
            for (int off = 32; off >= 1; off >>= 1) {
                ps += __shfl_xor(ps, off);
                pd += __shfl_xor(pd, off);
            }
            if (col == 0) {
                a_s[m0 + m] = ps;
                a_d[m0 + m] = pd;
            }
        }
    }
}

// -------------------------------------- per-dst-node softmax + aggregation
// One wave per node. Edge 0 = implicit self-loop; edges 1..deg from CSR.
// Online-softmax over chunks of 64 edges; shuffle-broadcast accumulate.
template <int H>
__global__ __launch_bounds__(256) void agg_k(const float* __restrict__ hmat, const float* __restrict__ a_s,
                                             const float* __restrict__ a_d, const int* __restrict__ offs,
                                             const int* __restrict__ csr_src, const float* __restrict__ bias,
                                             float* __restrict__ out, int N, int do_elu) {
    int node = (int)(((size_t)blockIdx.x * blockDim.x + threadIdx.x) >> 6);
    int lane = threadIdx.x & 63;
    if (node >= N) return;
    int beg = offs[node], end = offs[node + 1];
    int total = end - beg + 1;  // + self loop

    float m[H], den[H], acc[H], adl[H];
#pragma unroll
    for (int hh = 0; hh < H; hh++) {
        m[hh] = -3e38f; den[hh] = 0.f; acc[hh] = 0.f;
        adl[hh] = a_d[(size_t)node * H + hh];
    }

    for (int base = 0; base < total; base += 64) {
        int i = base + lane;
        bool valid = i < total;
        int s = node;
        if (valid && i > 0) s = csr_src[beg + i - 1];
        float e[H], p[H];
#pragma unroll
        for (int hh = 0; hh < H; hh++) {
            float v = a_s[(size_t)s * H + hh] + adl[hh];
            v = v > 0.f ? v : NEG_SLOPE * v;
            e[hh] = valid ? v : -3e38f;
        }
#pragma unroll
        for (int hh = 0; hh < H; hh++) {
            float cm = e[hh];
#pragma unroll
            for (int off = 32; off >= 1; off >>= 1) cm = fmaxf(cm, __shfl_xor(cm, off));
            float nm = fmaxf(m[hh], cm);
            float f = __expf(m[hh] - nm);   // 0 on first chunk
            p[hh] = __expf(e[hh] - nm);     // 0 for invalid lanes
            float ps = p[hh];
#pragma unroll
            for (int off = 32; off >= 1; off >>= 1) ps += __shfl_xor(ps, off);
            den[hh] = den[hh] * f + ps;
            acc[hh] *= f;
            m[hh] = nm;
        }
        int cn = total - base; if (cn > 64) cn = 64;
        for (int j = 0; j < cn; j++) {
            int sj = __shfl(s, j);
            const float* hrow = hmat + (size_t)sj * (H * 64);
#pragma unroll
            for (int hh = 0; hh < H; hh++) {
                float pj = __shfl(p[hh], j);
                acc[hh] = fmaf(hrow[hh * 64 + lane], pj, acc[hh]);
            }
        }
    }
#pragma unroll
    for (int hh = 0; hh < H; hh++) {
        float o = acc[hh] / (den[hh] + EPS) + bias[hh * 64 + lane];
        if (do_elu) o = o > 0.f ? o : expm1f(o);
        out[(size_t)node * (H * 64) + hh * 64 + lane] = o;
    }
}

// ------------------------------------------------------- final edge gather
__global__ void gather_k(const float* __restrict__ h2a, const int* __restrict__ srcv,
                         const int* __restrict__ dstv, float4* __restrict__ out, int E) {
    int t = blockIdx.x * blockDim.x + threadIdx.x;  // E*32 threads, float4 each
    if (t >= E * 32) return;
    int e = t >> 5, q = t & 31;
    int node = (q < 16) ? srcv[e] : dstv[e];
    out[t] = ((const float4*)(h2a + (size_t)node * 64))[q & 15];
}

// ---------------------------------------------------------------- launcher
extern "C" void kernel_launch(void* const* d_in, const int* in_sizes, int n_in,
                              void* d_out, int out_size, void* d_ws, size_t ws_size,
                              hipStream_t stream) {
    const float* x   = (const float*)d_in[0];
    const int*   ei  = (const int*)d_in[1];
    const float* W1  = (const float*)d_in[2];
    const float* aS1 = (const float*)d_in[3];
    const float* aD1 = (const float*)d_in[4];
    const float* b1  = (const float*)d_in[5];
    const float* W2  = (const float*)d_in[6];
    const float* aS2 = (const float*)d_in[7];
    const float* aD2 = (const float*)d_in[8];
    const float* b2  = (const float*)d_in[9];
    float* out = (float*)d_out;

    int N = in_sizes[0] / 128;
    int E = in_sizes[1] / 2;
    const int* srcv = ei;
    const int* dstv = ei + E;

    // workspace layout (256B-aligned slabs)
    size_t off = 0;
    char* base = (char*)d_ws;
    auto alloc = [&](size_t bytes) -> void* {
        void* p = base + off;
        off = (off + bytes + 255) & ~(size_t)255;
        return p;
    };
    int*   deg  = (int*)alloc((size_t)N * 4);
    int*   cur  = (int*)alloc((size_t)N * 4);
    int*   offs = (int*)alloc((size_t)(N + 1) * 4);
    int*   bsum = (int*)alloc(256 * 4);
    int*   csr  = (int*)alloc((size_t)E * 4);
    float* as1  = (float*)alloc((size_t)N * 4 * 4);
    float* ad1  = (float*)alloc((size_t)N * 4 * 4);
    float* h1   = (float*)alloc((size_t)N * 256 * 4);
    float* h1e  = (float*)alloc((size_t)N * 256 * 4);
    // layer-2 arrays alias the (dead-after-agg1) h1 slab
    float* h2   = h1;
    float* h2a  = h1 + (size_t)N * 64;
    float* as2  = h1 + (size_t)N * 128;
    float* ad2  = h1 + (size_t)N * 128 + N;

    hipMemsetAsync(deg, 0, (size_t)N * 4, stream);
    hipMemsetAsync(cur, 0, (size_t)N * 4, stream);

    int nbE = (E + 255) / 256;
    hist_k<<<nbE, 256, 0, stream>>>(dstv, E, deg);
    int nbS = (N + 1023) / 1024;
    scan1_k<<<nbS, 1024, 0, stream>>>(deg, offs, bsum, N);
    scan2_k<<<1, 64, 0, stream>>>(bsum, nbS);
    scan3_k<<<nbS, 1024, 0, stream>>>(offs, bsum, N, E);
    fill_k<<<nbE, 256, 0, stream>>>(srcv, dstv, E, offs, cur, csr);

    int nbM = (N + 15) / 16;
    gemm1_k<<<nbM, 256, 0, stream>>>(x, W1, aS1, aD1, h1, as1, ad1, N);

    int nbA = (N * 64 + 255) / 256;  // one wave per node
    agg_k<4><<<nbA, 256, 0, stream>>>(h1, as1, ad1, offs, csr, b1, h1e, N, 1);

    gemm2_k<<<nbM, 256, 0, stream>>>(h1e, W2, aS2, aD2, h2, as2, ad2, N);

    agg_k<1><<<nbA, 256, 0, stream>>>(h2, as2, ad2, offs, csr, b2, h2a, N, 0);

    int nbG = (E * 32 + 255) / 256;
    gather_k<<<nbG, 256, 0, stream>>>(h2a, srcv, dstv, (float4*)out, E);
}

// Round 3
// 477.602 us; speedup vs baseline: 1.1903x; 1.1903x over previous
//
#include <hip/hip_runtime.h>
#include <hip/hip_bf16.h>

#define NEG_SLOPE 0.2f
#define EPS 1e-16f

typedef float nfloat4 __attribute__((ext_vector_type(4)));

__device__ __forceinline__ float bf2f(unsigned short u) {
    union { unsigned int i; float f; } c; c.i = ((unsigned int)u) << 16; return c.f;
}

// ---------------------------------------------------------------- CSR build
__global__ void hist_k(const int* __restrict__ dst, int E, int* __restrict__ deg) {
    int e = blockIdx.x * blockDim.x + threadIdx.x;
    if (e < E) atomicAdd(&deg[dst[e]], 1);
}

__global__ __launch_bounds__(1024) void scan1_k(const int* __restrict__ deg, int* __restrict__ offs,
                                                int* __restrict__ bsum, int n) {
    __shared__ int tmp[1024];
    int t = threadIdx.x;
    int i = blockIdx.x * 1024 + t;
    int v = (i < n) ? deg[i] : 0;
    tmp[t] = v;
    __syncthreads();
    int run = v;
    for (int off = 1; off < 1024; off <<= 1) {
        int add = (t >= off) ? tmp[t - off] : 0;
        __syncthreads();
        run += add;
        tmp[t] = run;
        __syncthreads();
    }
    if (i < n) offs[i] = run - v;   // exclusive within block
    if (t == 1023) bsum[blockIdx.x] = run;
}

__global__ void scan2_k(int* bsum, int nb) {
    if (blockIdx.x == 0 && threadIdx.x == 0) {
        int acc = 0;
        for (int i = 0; i < nb; i++) { int v = bsum[i]; bsum[i] = acc; acc += v; }
    }
}

__global__ __launch_bounds__(1024) void scan3_k(int* __restrict__ offs, const int* __restrict__ bsum,
                                                int n, int total) {
    int i = blockIdx.x * 1024 + threadIdx.x;
    if (i < n) offs[i] += bsum[blockIdx.x];
    if (i == 0) offs[n] = total;
}

__global__ void fill_k(const int* __restrict__ src, const int* __restrict__ dst, int E,
                       const int* __restrict__ offs, int* __restrict__ cur, int* __restrict__ csr) {
    int e = blockIdx.x * blockDim.x + threadIdx.x;
    if (e >= E) return;
    int d = dst[e];
    int pos = offs[d] + atomicAdd(&cur[d], 1);
    csr[pos] = src[e];
}

// ------------------------------------------------- GEMM1: [N,128]x[128,256]
// Writes h1 as packed bf16, head-interleaved: h1b[node][lane][head] (ushort4/lane).
// Fused epilogue: per-head attention dots in fp32 (each wave = one head's 64 cols).
__global__ __launch_bounds__(256) void gemm1_k(const float* __restrict__ x, const float* __restrict__ W1,
                                               const float* __restrict__ attS, const float* __restrict__ attD,
                                               ushort* __restrict__ h1b, float* __restrict__ a_s,
                                               float* __restrict__ a_d, int N) {
    __shared__ float xs[16][128];   // 8 KB; reused as bf16 staging (16*256 ushort = 8 KB)
    int m0 = blockIdx.x * 16;
    int t = threadIdx.x;
    int rows = N - m0; if (rows > 16) rows = 16;

    if (rows == 16) {
        const float4* xv = (const float4*)(x + (size_t)m0 * 128);
        float4* xsv = (float4*)(&xs[0][0]);
        xsv[t] = xv[t];
        xsv[t + 256] = xv[t + 256];
    } else {
        for (int i = t; i < rows * 128; i += 256) xs[i >> 7][i & 127] = x[(size_t)m0 * 128 + i];
    }
    __syncthreads();

    float acc[16];
#pragma unroll
    for (int m = 0; m < 16; m++) acc[m] = 0.f;
    for (int k = 0; k < 128; k++) {
        float w = W1[k * 256 + t];
#pragma unroll
        for (int m = 0; m < 16; m++) acc[m] = fmaf(xs[m][k], w, acc[m]);
    }
    __syncthreads();   // done reading xs; reuse as staging

    ushort* hs = (ushort*)&xs[0][0];
    int lane = t & 63;
    int head = t >> 6;
    float asv = attS[t], adv = attD[t];
    for (int m = 0; m < rows; m++) {
        __hip_bfloat16 hb = __float2bfloat16(acc[m]);
        hs[m * 256 + lane * 4 + head] = *(ushort*)&hb;
        float ps = acc[m] * asv, pd = acc[m] * adv;
#pragma unroll
        for (int off = 32; off >= 1; off >>= 1) {
            ps += __shfl_xor(ps, off);
            pd += __shfl_xor(pd, off);
        }
        if (lane == 0) {
            a_s[(size_t)(m0 + m) * 4 + head] = ps;
            a_d[(size_t)(m0 + m) * 4 + head] = pd;
        }
    }
    __syncthreads();

    ushort4* dst4 = (ushort4*)h1b + (size_t)m0 * 64;
    const ushort4* s4 = (const ushort4*)hs;
    for (int i = t; i < rows * 64; i += 256) dst4[i] = s4[i];
}

// ------------------------------------------------- GEMM2: [N,256]x[256,64]
__global__ __launch_bounds__(256) void gemm2_k(const float* __restrict__ h1e, const float* __restrict__ W2,
                                               const float* __restrict__ attS, const float* __restrict__ attD,
                                               float* __restrict__ h2, float* __restrict__ a_s,
                                               float* __restrict__ a_d, int N) {
    __shared__ float xs[16][256];
    int m0 = blockIdx.x * 16;
    int t = threadIdx.x;
    int rows = N - m0; if (rows > 16) rows = 16;

    if (rows == 16) {
        const float4* xv = (const float4*)(h1e + (size_t)m0 * 256);
        float4* xsv = (float4*)(&xs[0][0]);
#pragma unroll
        for (int i = 0; i < 4; i++) xsv[t + 256 * i] = xv[t + 256 * i];
    } else {
        for (int i = t; i < rows * 256; i += 256) xs[i >> 8][i & 255] = h1e[(size_t)m0 * 256 + i];
    }
    __syncthreads();

    int col = t & 63, mg = t >> 6;   // wave-uniform mg
    float acc[4] = {0.f, 0.f, 0.f, 0.f};
    for (int k = 0; k < 256; k++) {
        float w = W2[k * 64 + col];
#pragma unroll
        for (int mm = 0; mm < 4; mm++) acc[mm] = fmaf(xs[mg + 4 * mm][k], w, acc[mm]);
    }
    float asv = attS[col], adv = attD[col];
#pragma unroll
    for (int mm = 0; mm < 4; mm++) {
        int m = mg + 4 * mm;
        if (m < rows) {
            h2[(size_t)(m0 + m) * 64 + col] = acc[mm];
            float ps = acc[mm] * asv, pd = acc[mm] * adv;
#pragma unroll
            for (int off = 32; off >= 1; off >>= 1) {
                ps += __shfl_xor(ps, off);
                pd += __shfl_xor(pd, off);
            }
            if (col == 0) {
                a_s[m0 + m] = ps;
                a_d[m0 + m] = pd;
            }
        }
    }
}

// --------------------------- layer-1 softmax+aggregate (4 heads, bf16 msgs)
// One wave per node. Edge 0 = implicit self-loop; edges 1..deg from CSR.
// No max-subtraction (|e| small -> exp safe). j-loop unrolled x4.
__global__ __launch_bounds__(256) void agg4_k(const ushort4* __restrict__ hb, const float4* __restrict__ asv,
                                              const float4* __restrict__ adv, const int* __restrict__ offs,
                                              const int* __restrict__ csr, const float* __restrict__ bias,
                                              float* __restrict__ out, int N) {
    int node = (int)(((size_t)blockIdx.x * blockDim.x + threadIdx.x) >> 6);
    int lane = threadIdx.x & 63;
    if (node >= N) return;
    int beg = offs[node], end = offs[node + 1];
    int total = end - beg + 1;  // + self loop
    float4 ad = adv[node];

    float den0 = 0.f, den1 = 0.f, den2 = 0.f, den3 = 0.f;
    float acc0 = 0.f, acc1 = 0.f, acc2 = 0.f, acc3 = 0.f;

    for (int base = 0; base < total; base += 64) {
        int i = base + lane;
        bool valid = i < total;
        int s = node;
        if (valid && i > 0) s = csr[beg + i - 1];
        float4 av = asv[s];
        float e0 = av.x + ad.x; e0 = e0 > 0.f ? e0 : NEG_SLOPE * e0;
        float e1 = av.y + ad.y; e1 = e1 > 0.f ? e1 : NEG_SLOPE * e1;
        float e2 = av.z + ad.z; e2 = e2 > 0.f ? e2 : NEG_SLOPE * e2;
        float e3 = av.w + ad.w; e3 = e3 > 0.f ? e3 : NEG_SLOPE * e3;
        float p0 = valid ? __expf(e0) : 0.f;
        float p1 = valid ? __expf(e1) : 0.f;
        float p2 = valid ? __expf(e2) : 0.f;
        float p3 = valid ? __expf(e3) : 0.f;
        float q0 = p0, q1 = p1, q2 = p2, q3 = p3;
#pragma unroll
        for (int off = 32; off >= 1; off >>= 1) {
            q0 += __shfl_xor(q0, off);
            q1 += __shfl_xor(q1, off);
            q2 += __shfl_xor(q2, off);
            q3 += __shfl_xor(q3, off);
        }
        den0 += q0; den1 += q1; den2 += q2; den3 += q3;

        int cn = total - base; if (cn > 64) cn = 64;
        int cn4 = (cn + 3) & ~3;
        for (int j = 0; j < cn4; j += 4) {
            int s0 = __shfl(s, j), s1 = __shfl(s, j + 1), s2 = __shfl(s, j + 2), s3 = __shfl(s, j + 3);
            ushort4 v0 = hb[(size_t)s0 * 64 + lane];
            ushort4 v1 = hb[(size_t)s1 * 64 + lane];
            ushort4 v2 = hb[(size_t)s2 * 64 + lane];
            ushort4 v3 = hb[(size_t)s3 * 64 + lane];
            float w00 = __shfl(p0, j), w01 = __shfl(p1, j), w02 = __shfl(p2, j), w03 = __shfl(p3, j);
            acc0 = fmaf(bf2f(v0.x), w00, acc0);
            acc1 = fmaf(bf2f(v0.y), w01, acc1);
            acc2 = fmaf(bf2f(v0.z), w02, acc2);
            acc3 = fmaf(bf2f(v0.w), w03, acc3);
            float w10 = __shfl(p0, j + 1), w11 = __shfl(p1, j + 1), w12 = __shfl(p2, j + 1), w13 = __shfl(p3, j + 1);
            acc0 = fmaf(bf2f(v1.x), w10, acc0);
            acc1 = fmaf(bf2f(v1.y), w11, acc1);
            acc2 = fmaf(bf2f(v1.z), w12, acc2);
            acc3 = fmaf(bf2f(v1.w), w13, acc3);
            float w20 = __shfl(p0, j + 2), w21 = __shfl(p1, j + 2), w22 = __shfl(p2, j + 2), w23 = __shfl(p3, j + 2);
            acc0 = fmaf(bf2f(v2.x), w20, acc0);
            acc1 = fmaf(bf2f(v2.y), w21, acc1);
            acc2 = fmaf(bf2f(v2.z), w22, acc2);
            acc3 = fmaf(bf2f(v2.w), w23, acc3);
            float w30 = __shfl(p0, j + 3), w31 = __shfl(p1, j + 3), w32 = __shfl(p2, j + 3), w33 = __shfl(p3, j + 3);
            acc0 = fmaf(bf2f(v3.x), w30, acc0);
            acc1 = fmaf(bf2f(v3.y), w31, acc1);
            acc2 = fmaf(bf2f(v3.z), w32, acc2);
            acc3 = fmaf(bf2f(v3.w), w33, acc3);
        }
    }

    float o;
    o = acc0 / (den0 + EPS) + bias[lane];
    o = o > 0.f ? o : expm1f(o);
    out[(size_t)node * 256 + lane] = o;
    o = acc1 / (den1 + EPS) + bias[64 + lane];
    o = o > 0.f ? o : expm1f(o);
    out[(size_t)node * 256 + 64 + lane] = o;
    o = acc2 / (den2 + EPS) + bias[128 + lane];
    o = o > 0.f ? o : expm1f(o);
    out[(size_t)node * 256 + 128 + lane] = o;
    o = acc3 / (den3 + EPS) + bias[192 + lane];
    o = o > 0.f ? o : expm1f(o);
    out[(size_t)node * 256 + 192 + lane] = o;
}

// --------------------------- layer-2 softmax+aggregate (1 head, fp32 msgs)
__global__ __launch_bounds__(256) void agg1_k(const float* __restrict__ h2, const float* __restrict__ asv,
                                              const float* __restrict__ adv, const int* __restrict__ offs,
                                              const int* __restrict__ csr, const float* __restrict__ bias,
                                              float* __restrict__ out, int N) {
    int node = (int)(((size_t)blockIdx.x * blockDim.x + threadIdx.x) >> 6);
    int lane = threadIdx.x & 63;
    if (node >= N) return;
    int beg = offs[node], end = offs[node + 1];
    int total = end - beg + 1;
    float ad = adv[node];

    float den = 0.f, acc = 0.f;
    for (int base = 0; base < total; base += 64) {
        int i = base + lane;
        bool valid = i < total;
        int s = node;
        if (valid && i > 0) s = csr[beg + i - 1];
        float e = asv[s] + ad;
        e = e > 0.f ? e : NEG_SLOPE * e;
        float p = valid ? __expf(e) : 0.f;
        float q = p;
#pragma unroll
        for (int off = 32; off >= 1; off >>= 1) q += __shfl_xor(q, off);
        den += q;

        int cn = total - base; if (cn > 64) cn = 64;
        int cn4 = (cn + 3) & ~3;
        for (int j = 0; j < cn4; j += 4) {
            int s0 = __shfl(s, j), s1 = __shfl(s, j + 1), s2 = __shfl(s, j + 2), s3 = __shfl(s, j + 3);
            float h0 = h2[(size_t)s0 * 64 + lane];
            float h1 = h2[(size_t)s1 * 64 + lane];
            float h2v = h2[(size_t)s2 * 64 + lane];
            float h3 = h2[(size_t)s3 * 64 + lane];
            acc = fmaf(h0, __shfl(p, j), acc);
            acc = fmaf(h1, __shfl(p, j + 1), acc);
            acc = fmaf(h2v, __shfl(p, j + 2), acc);
            acc = fmaf(h3, __shfl(p, j + 3), acc);
        }
    }
    out[(size_t)node * 64 + lane] = acc / (den + EPS) + bias[lane];
}

// ------------------------------------------------------- final edge gather
__global__ void gather_k(const nfloat4* __restrict__ h2a4, const int* __restrict__ srcv,
                         const int* __restrict__ dstv, nfloat4* __restrict__ out, int E) {
    int t = blockIdx.x * blockDim.x + threadIdx.x;  // E*32 threads, 16B each
    if (t >= E * 32) return;
    int e = t >> 5, q = t & 31;
    int node = (q < 16) ? srcv[e] : dstv[e];
    nfloat4 v = h2a4[(size_t)node * 16 + (q & 15)];
    __builtin_nontemporal_store(v, &out[t]);
}

// ---------------------------------------------------------------- launcher
extern "C" void kernel_launch(void* const* d_in, const int* in_sizes, int n_in,
                              void* d_out, int out_size, void* d_ws, size_t ws_size,
                              hipStream_t stream) {
    const float* x   = (const float*)d_in[0];
    const int*   ei  = (const int*)d_in[1];
    const float* W1  = (const float*)d_in[2];
    const float* aS1 = (const float*)d_in[3];
    const float* aD1 = (const float*)d_in[4];
    const float* b1  = (const float*)d_in[5];
    const float* W2  = (const float*)d_in[6];
    const float* aS2 = (const float*)d_in[7];
    const float* aD2 = (const float*)d_in[8];
    const float* b2  = (const float*)d_in[9];
    float* out = (float*)d_out;

    int N = in_sizes[0] / 128;
    int E = in_sizes[1] / 2;
    const int* srcv = ei;
    const int* dstv = ei + E;

    size_t off = 0;
    char* base = (char*)d_ws;
    auto alloc = [&](size_t bytes) -> void* {
        void* p = base + off;
        off = (off + bytes + 255) & ~(size_t)255;
        return p;
    };
    int*    deg  = (int*)alloc((size_t)N * 4);
    int*    cur  = (int*)alloc((size_t)N * 4);
    int*    offs = (int*)alloc((size_t)(N + 1) * 4);
    int*    bsum = (int*)alloc(256 * 4);
    int*    csr  = (int*)alloc((size_t)E * 4);
    float*  as1  = (float*)alloc((size_t)N * 4 * 4);
    float*  ad1  = (float*)alloc((size_t)N * 4 * 4);
    float*  as2  = (float*)alloc((size_t)N * 4);
    float*  ad2  = (float*)alloc((size_t)N * 4);
    ushort* h1b  = (ushort*)alloc((size_t)N * 256 * 2);   // bf16 packed [N][64][4]
    float*  h1e  = (float*)alloc((size_t)N * 256 * 4);    // fp32 [N][256]
    // layer-2 fp32 arrays alias the (dead-after-agg) h1b slab (2*12.8 MB needed, 25.6 MB avail)
    float*  h2   = (float*)h1b;
    float*  h2a  = (float*)h1b + (size_t)N * 64;

    (void)hipMemsetAsync(deg, 0, (size_t)N * 4, stream);
    (void)hipMemsetAsync(cur, 0, (size_t)N * 4, stream);

    int nbE = (E + 255) / 256;
    hist_k<<<nbE, 256, 0, stream>>>(dstv, E, deg);
    int nbS = (N + 1023) / 1024;
    scan1_k<<<nbS, 1024, 0, stream>>>(deg, offs, bsum, N);
    scan2_k<<<1, 64, 0, stream>>>(bsum, nbS);
    scan3_k<<<nbS, 1024, 0, stream>>>(offs, bsum, N, E);
    fill_k<<<nbE, 256, 0, stream>>>(srcv, dstv, E, offs, cur, csr);

    int nbM = (N + 15) / 16;
    gemm1_k<<<nbM, 256, 0, stream>>>(x, W1, aS1, aD1, h1b, as1, ad1, N);

    int nbA = (N * 64 + 255) / 256;  // one wave per node
    agg4_k<<<nbA, 256, 0, stream>>>((const ushort4*)h1b, (const float4*)as1, (const float4*)ad1,
                                    offs, csr, b1, h1e, N);

    gemm2_k<<<nbM, 256, 0, stream>>>(h1e, W2, aS2, aD2, h2, as2, ad2, N);

    agg1_k<<<nbA, 256, 0, stream>>>(h2, as2, ad2, offs, csr, b2, h2a, N);

    int nbG = (E * 32 + 255) / 256;
    gather_k<<<nbG, 256, 0, stream>>>((const nfloat4*)h2a, srcv, dstv, (nfloat4*)out, E);
}

// Round 4
// 362.719 us; speedup vs baseline: 1.5673x; 1.3167x over previous
//
#include <hip/hip_runtime.h>
#include <hip/hip_bf16.h>

#define NEG_SLOPE 0.2f
#define EPS 1e-16f

typedef short  bf16x8  __attribute__((ext_vector_type(8)));
typedef float  f32x4   __attribute__((ext_vector_type(4)));
typedef float  nfloat4 __attribute__((ext_vector_type(4)));

__device__ __forceinline__ float bf2f(unsigned short u) {
    union { unsigned int i; float f; } c; c.i = ((unsigned int)u) << 16; return c.f;
}
__device__ __forceinline__ ushort f2bf(float f) {
    __hip_bfloat16 b = __float2bfloat16(f);
    return *(ushort*)&b;
}

// ---------------------------------------------------------------- CSR build
__global__ void hist_k(const int* __restrict__ dst, int E, int* __restrict__ deg) {
    int e = blockIdx.x * blockDim.x + threadIdx.x;
    if (e < E) atomicAdd(&deg[dst[e]], 1);
}

__global__ __launch_bounds__(1024) void scan1_k(const int* __restrict__ deg, int* __restrict__ offs,
                                                int* __restrict__ bsum, int n) {
    __shared__ int tmp[1024];
    int t = threadIdx.x;
    int i = blockIdx.x * 1024 + t;
    int v = (i < n) ? deg[i] : 0;
    tmp[t] = v;
    __syncthreads();
    int run = v;
    for (int off = 1; off < 1024; off <<= 1) {
        int add = (t >= off) ? tmp[t - off] : 0;
        __syncthreads();
        run += add;
        tmp[t] = run;
        __syncthreads();
    }
    if (i < n) offs[i] = run - v;
    if (t == 1023) bsum[blockIdx.x] = run;
}

__global__ void scan2_k(int* bsum, int nb) {
    if (blockIdx.x == 0 && threadIdx.x == 0) {
        int acc = 0;
        for (int i = 0; i < nb; i++) { int v = bsum[i]; bsum[i] = acc; acc += v; }
    }
}

__global__ __launch_bounds__(1024) void scan3_k(int* __restrict__ offs, const int* __restrict__ bsum,
                                                int n, int total) {
    int i = blockIdx.x * 1024 + threadIdx.x;
    if (i < n) offs[i] += bsum[blockIdx.x];
    if (i == 0) offs[n] = total;
}

__global__ void fill_k(const int* __restrict__ src, const int* __restrict__ dst, int E,
                       const int* __restrict__ offs, int* __restrict__ cur, int* __restrict__ csr) {
    int e = blockIdx.x * blockDim.x + threadIdx.x;
    if (e >= E) return;
    int d = dst[e];
    int pos = offs[d] + atomicAdd(&cur[d], 1);
    csr[pos] = src[e];
}

// ------------------------------------------- x -> (hi,lo) bf16 split
__global__ void convx_k(const float4* __restrict__ xv, ushort4* __restrict__ xhi4,
                        ushort4* __restrict__ xlo4, int n4) {
    int t = blockIdx.x * blockDim.x + threadIdx.x;
    if (t >= n4) return;
    float4 v = xv[t];
    ushort4 h, l;
    h.x = f2bf(v.x); l.x = f2bf(v.x - bf2f(h.x));
    h.y = f2bf(v.y); l.y = f2bf(v.y - bf2f(h.y));
    h.z = f2bf(v.z); l.z = f2bf(v.z - bf2f(h.z));
    h.w = f2bf(v.w); l.w = f2bf(v.w - bf2f(h.w));
    xhi4[t] = h; xlo4[t] = l;
}

// ---------------- W1aug (128 x 272: 256 cols + 4 a_s + 4 a_d + 8 pad) in frag order
// frag idx: ((nt*4+ks)*64 + lane)*8 + j ; k = ks*32+(lane>>4)*8+j ; col = nt*16+(lane&15)
__global__ void wprep1_k(const float* __restrict__ W1, const float* __restrict__ attS,
                         const float* __restrict__ attD, ushort* __restrict__ bhi,
                         ushort* __restrict__ blo) {
    int tid = blockIdx.x * blockDim.x + threadIdx.x;
    if (tid >= 17 * 4 * 64 * 8) return;
    int j = tid & 7, lane = (tid >> 3) & 63, ks = (tid >> 9) & 3, nt = tid >> 11;
    int k = ks * 32 + (lane >> 4) * 8 + j;
    int col = nt * 16 + (lane & 15);
    float v = 0.f;
    if (col < 256) v = W1[k * 256 + col];
    else if (col < 264) {
        int cc = col - 256, h = cc & 3;
        const float* att = (cc < 4) ? attS : attD;
        float s = 0.f;
        for (int c = 0; c < 64; c++) s += W1[k * 256 + h * 64 + c] * att[h * 64 + c];
        v = s;
    }
    ushort hi = f2bf(v);
    float rem = v - bf2f(hi);
    int idx = ((nt * 4 + ks) * 64 + lane) * 8 + j;
    bhi[idx] = hi; blo[idx] = f2bf(rem);
}

// ---------------- W2aug (256 x 80: 64 cols + a_s + a_d + 14 pad) in frag order
__global__ void wprep2_k(const float* __restrict__ W2, const float* __restrict__ attS,
                         const float* __restrict__ attD, ushort* __restrict__ bhi,
                         ushort* __restrict__ blo) {
    int tid = blockIdx.x * blockDim.x + threadIdx.x;
    if (tid >= 5 * 8 * 64 * 8) return;
    int j = tid & 7, lane = (tid >> 3) & 63, ks = (tid >> 9) & 7, nt = tid >> 12;
    int k = ks * 32 + (lane >> 4) * 8 + j;
    int col = nt * 16 + (lane & 15);
    float v = 0.f;
    if (col < 64) v = W2[k * 64 + col];
    else if (col == 64) { float s = 0.f; for (int c = 0; c < 64; c++) s += W2[k * 64 + c] * attS[c]; v = s; }
    else if (col == 65) { float s = 0.f; for (int c = 0; c < 64; c++) s += W2[k * 64 + c] * attD[c]; v = s; }
    ushort hi = f2bf(v);
    float rem = v - bf2f(hi);
    int idx = ((nt * 8 + ks) * 64 + lane) * 8 + j;
    bhi[idx] = hi; blo[idx] = f2bf(rem);
}

// ------------------------------- GEMM1 MFMA: [N,128]x[128,272] split-bf16
// One wave per 16-row strip. Outputs packed bf16 h1b[node][c][head] + f32 dots.
__global__ __launch_bounds__(256) void gemm1_mfma_k(const ushort* __restrict__ xhi, const ushort* __restrict__ xlo,
                                                    const bf16x8* __restrict__ bhi, const bf16x8* __restrict__ blo,
                                                    ushort* __restrict__ h1b, float* __restrict__ as1,
                                                    float* __restrict__ ad1, int N) {
    __shared__ ushort hs[4][16][256];
    int wid = threadIdx.x >> 6, lane = threadIdx.x & 63;
    int m0 = (blockIdx.x * 4 + wid) * 16;
    if (m0 >= N) return;
    int row = lane & 15, grp = lane >> 4;
    const bf16x8* xhi8 = (const bf16x8*)xhi;
    const bf16x8* xlo8 = (const bf16x8*)xlo;
    bf16x8 ah[4], al[4];
    size_t rb = (size_t)(m0 + row) * 16 + grp;   // 16 groups of 8 per 128-row
#pragma unroll
    for (int ks = 0; ks < 4; ks++) { ah[ks] = xhi8[rb + ks * 4]; al[ks] = xlo8[rb + ks * 4]; }

    for (int nt = 0; nt < 17; nt++) {
        f32x4 acc = {0.f, 0.f, 0.f, 0.f};
#pragma unroll
        for (int ks = 0; ks < 4; ks++) {
            bf16x8 bh = bhi[(nt * 4 + ks) * 64 + lane];
            bf16x8 bl = blo[(nt * 4 + ks) * 64 + lane];
            acc = __builtin_amdgcn_mfma_f32_16x16x32_bf16(ah[ks], bh, acc, 0, 0, 0);
            acc = __builtin_amdgcn_mfma_f32_16x16x32_bf16(al[ks], bh, acc, 0, 0, 0);
            acc = __builtin_amdgcn_mfma_f32_16x16x32_bf16(ah[ks], bl, acc, 0, 0, 0);
        }
        if (nt < 16) {
            int col = nt * 16 + row, head = col >> 6, c = col & 63;
#pragma unroll
            for (int r = 0; r < 4; r++) hs[wid][grp * 4 + r][c * 4 + head] = f2bf(acc[r]);
        } else if (row < 8) {
#pragma unroll
            for (int r = 0; r < 4; r++) {
                int node = m0 + grp * 4 + r;
                if (row < 4) as1[node * 4 + row] = acc[r];
                else         ad1[node * 4 + (row - 4)] = acc[r];
            }
        }
    }
    ushort4* dst = (ushort4*)h1b + (size_t)m0 * 64;
    const ushort4* s4 = (const ushort4*)&hs[wid][0][0];
    for (int i = lane; i < 1024; i += 64) dst[i] = s4[i];
}

// ------------------------------- GEMM2 MFMA: [N,256]x[256,80], A bf16, W split
__global__ __launch_bounds__(256) void gemm2_mfma_k(const ushort* __restrict__ h1e,
                                                    const bf16x8* __restrict__ bhi, const bf16x8* __restrict__ blo,
                                                    ushort* __restrict__ h2b, float* __restrict__ as2,
                                                    float* __restrict__ ad2, int N) {
    __shared__ ushort hs[4][16][64];
    int wid = threadIdx.x >> 6, lane = threadIdx.x & 63;
    int m0 = (blockIdx.x * 4 + wid) * 16;
    if (m0 >= N) return;
    int row = lane & 15, grp = lane >> 4;
    const bf16x8* a8 = (const bf16x8*)h1e;
    bf16x8 a[8];
    size_t rb = (size_t)(m0 + row) * 32 + grp;   // 32 groups of 8 per 256-row
#pragma unroll
    for (int ks = 0; ks < 8; ks++) a[ks] = a8[rb + ks * 4];

    for (int nt = 0; nt < 5; nt++) {
        f32x4 acc = {0.f, 0.f, 0.f, 0.f};
#pragma unroll
        for (int ks = 0; ks < 8; ks++) {
            bf16x8 bh = bhi[(nt * 8 + ks) * 64 + lane];
            bf16x8 bl = blo[(nt * 8 + ks) * 64 + lane];
            acc = __builtin_amdgcn_mfma_f32_16x16x32_bf16(a[ks], bh, acc, 0, 0, 0);
            acc = __builtin_amdgcn_mfma_f32_16x16x32_bf16(a[ks], bl, acc, 0, 0, 0);
        }
        if (nt < 4) {
            int col = nt * 16 + row;
#pragma unroll
            for (int r = 0; r < 4; r++) hs[wid][grp * 4 + r][col] = f2bf(acc[r]);
        } else if (row < 2) {
#pragma unroll
            for (int r = 0; r < 4; r++) {
                int node = m0 + grp * 4 + r;
                if (row == 0) as2[node] = acc[r];
                else          ad2[node] = acc[r];
            }
        }
    }
    ushort4* dst = (ushort4*)h2b + (size_t)m0 * 16;
    const ushort4* s4 = (const ushort4*)&hs[wid][0][0];
    for (int i = lane; i < 256; i += 64) dst[i] = s4[i];
}

// --------------------------- layer-1 softmax+aggregate (4 heads, bf16 msgs)
__global__ __launch_bounds__(256) void agg4_k(const ushort4* __restrict__ hb, const float4* __restrict__ asv,
                                              const float4* __restrict__ adv, const int* __restrict__ offs,
                                              const int* __restrict__ csr, const float* __restrict__ bias,
                                              ushort* __restrict__ out, int N) {
    int node = (int)(((size_t)blockIdx.x * blockDim.x + threadIdx.x) >> 6);
    int lane = threadIdx.x & 63;
    if (node >= N) return;
    int beg = offs[node], end = offs[node + 1];
    int total = end - beg + 1;
    float4 ad = adv[node];

    float den0 = 0.f, den1 = 0.f, den2 = 0.f, den3 = 0.f;
    float acc0 = 0.f, acc1 = 0.f, acc2 = 0.f, acc3 = 0.f;

    for (int base = 0; base < total; base += 64) {
        int i = base + lane;
        bool valid = i < total;
        int s = node;
        if (valid && i > 0) s = csr[beg + i - 1];
        float4 av = asv[s];
        float e0 = av.x + ad.x; e0 = e0 > 0.f ? e0 : NEG_SLOPE * e0;
        float e1 = av.y + ad.y; e1 = e1 > 0.f ? e1 : NEG_SLOPE * e1;
        float e2 = av.z + ad.z; e2 = e2 > 0.f ? e2 : NEG_SLOPE * e2;
        float e3 = av.w + ad.w; e3 = e3 > 0.f ? e3 : NEG_SLOPE * e3;
        float p0 = valid ? __expf(e0) : 0.f;
        float p1 = valid ? __expf(e1) : 0.f;
        float p2 = valid ? __expf(e2) : 0.f;
        float p3 = valid ? __expf(e3) : 0.f;
        float q0 = p0, q1 = p1, q2 = p2, q3 = p3;
#pragma unroll
        for (int off = 32; off >= 1; off >>= 1) {
            q0 += __shfl_xor(q0, off);
            q1 += __shfl_xor(q1, off);
            q2 += __shfl_xor(q2, off);
            q3 += __shfl_xor(q3, off);
        }
        den0 += q0; den1 += q1; den2 += q2; den3 += q3;

        int cn = total - base; if (cn > 64) cn = 64;
        int cn4 = (cn + 3) & ~3;
        for (int j = 0; j < cn4; j += 4) {
            int s0 = __shfl(s, j), s1 = __shfl(s, j + 1), s2 = __shfl(s, j + 2), s3 = __shfl(s, j + 3);
            ushort4 v0 = hb[(size_t)s0 * 64 + lane];
            ushort4 v1 = hb[(size_t)s1 * 64 + lane];
            ushort4 v2 = hb[(size_t)s2 * 64 + lane];
            ushort4 v3 = hb[(size_t)s3 * 64 + lane];
            float w00 = __shfl(p0, j), w01 = __shfl(p1, j), w02 = __shfl(p2, j), w03 = __shfl(p3, j);
            acc0 = fmaf(bf2f(v0.x), w00, acc0);
            acc1 = fmaf(bf2f(v0.y), w01, acc1);
            acc2 = fmaf(bf2f(v0.z), w02, acc2);
            acc3 = fmaf(bf2f(v0.w), w03, acc3);
            float w10 = __shfl(p0, j + 1), w11 = __shfl(p1, j + 1), w12 = __shfl(p2, j + 1), w13 = __shfl(p3, j + 1);
            acc0 = fmaf(bf2f(v1.x), w10, acc0);
            acc1 = fmaf(bf2f(v1.y), w11, acc1);
            acc2 = fmaf(bf2f(v1.z), w12, acc2);
            acc3 = fmaf(bf2f(v1.w), w13, acc3);
            float w20 = __shfl(p0, j + 2), w21 = __shfl(p1, j + 2), w22 = __shfl(p2, j + 2), w23 = __shfl(p3, j + 2);
            acc0 = fmaf(bf2f(v2.x), w20, acc0);
            acc1 = fmaf(bf2f(v2.y), w21, acc1);
            acc2 = fmaf(bf2f(v2.z), w22, acc2);
            acc3 = fmaf(bf2f(v2.w), w23, acc3);
            float w30 = __shfl(p0, j + 3), w31 = __shfl(p1, j + 3), w32 = __shfl(p2, j + 3), w33 = __shfl(p3, j + 3);
            acc0 = fmaf(bf2f(v3.x), w30, acc0);
            acc1 = fmaf(bf2f(v3.y), w31, acc1);
            acc2 = fmaf(bf2f(v3.z), w32, acc2);
            acc3 = fmaf(bf2f(v3.w), w33, acc3);
        }
    }

    ushort* op = out + (size_t)node * 256 + lane;
    float o;
    o = acc0 / (den0 + EPS) + bias[lane];        o = o > 0.f ? o : expm1f(o); op[0]   = f2bf(o);
    o = acc1 / (den1 + EPS) + bias[64 + lane];   o = o > 0.f ? o : expm1f(o); op[64]  = f2bf(o);
    o = acc2 / (den2 + EPS) + bias[128 + lane];  o = o > 0.f ? o : expm1f(o); op[128] = f2bf(o);
    o = acc3 / (den3 + EPS) + bias[192 + lane];  o = o > 0.f ? o : expm1f(o); op[192] = f2bf(o);
}

// --------------------------- layer-2 softmax+aggregate (1 head, bf16 msgs)
__global__ __launch_bounds__(256) void agg1_k(const ushort* __restrict__ h2b, const float* __restrict__ asv,
                                              const float* __restrict__ adv, const int* __restrict__ offs,
                                              const int* __restrict__ csr, const float* __restrict__ bias,
                                              float* __restrict__ out, int N) {
    int node = (int)(((size_t)blockIdx.x * blockDim.x + threadIdx.x) >> 6);
    int lane = threadIdx.x & 63;
    if (node >= N) return;
    int beg = offs[node], end = offs[node + 1];
    int total = end - beg + 1;
    float ad = adv[node];

    float den = 0.f, acc = 0.f;
    for (int base = 0; base < total; base += 64) {
        int i = base + lane;
        bool valid = i < total;
        int s = node;
        if (valid && i > 0) s = csr[beg + i - 1];
        float e = asv[s] + ad;
        e = e > 0.f ? e : NEG_SLOPE * e;
        float p = valid ? __expf(e) : 0.f;
        float q = p;
#pragma unroll
        for (int off = 32; off >= 1; off >>= 1) q += __shfl_xor(q, off);
        den += q;

        int cn = total - base; if (cn > 64) cn = 64;
        int cn4 = (cn + 3) & ~3;
        for (int j = 0; j < cn4; j += 4) {
            int s0 = __shfl(s, j), s1 = __shfl(s, j + 1), s2 = __shfl(s, j + 2), s3 = __shfl(s, j + 3);
            float h0 = bf2f(h2b[(size_t)s0 * 64 + lane]);
            float h1 = bf2f(h2b[(size_t)s1 * 64 + lane]);
            float h2v = bf2f(h2b[(size_t)s2 * 64 + lane]);
            float h3 = bf2f(h2b[(size_t)s3 * 64 + lane]);
            acc = fmaf(h0, __shfl(p, j), acc);
            acc = fmaf(h1, __shfl(p, j + 1), acc);
            acc = fmaf(h2v, __shfl(p, j + 2), acc);
            acc = fmaf(h3, __shfl(p, j + 3), acc);
        }
    }
    out[(size_t)node * 64 + lane] = acc / (den + EPS) + bias[lane];
}

// ------------------------------------------------------- final edge gather
__global__ void gather_k(const nfloat4* __restrict__ h2a4, const int* __restrict__ srcv,
                         const int* __restrict__ dstv, nfloat4* __restrict__ out, int E) {
    int t = blockIdx.x * blockDim.x + threadIdx.x;
    if (t >= E * 32) return;
    int e = t >> 5, q = t & 31;
    int node = (q < 16) ? srcv[e] : dstv[e];
    nfloat4 v = h2a4[(size_t)node * 16 + (q & 15)];
    __builtin_nontemporal_store(v, &out[t]);
}

// ---------------------------------------------------------------- launcher
extern "C" void kernel_launch(void* const* d_in, const int* in_sizes, int n_in,
                              void* d_out, int out_size, void* d_ws, size_t ws_size,
                              hipStream_t stream) {
    const float* x   = (const float*)d_in[0];
    const int*   ei  = (const int*)d_in[1];
    const float* W1  = (const float*)d_in[2];
    const float* aS1 = (const float*)d_in[3];
    const float* aD1 = (const float*)d_in[4];
    const float* b1  = (const float*)d_in[5];
    const float* W2  = (const float*)d_in[6];
    const float* aS2 = (const float*)d_in[7];
    const float* aD2 = (const float*)d_in[8];
    const float* b2  = (const float*)d_in[9];
    float* out = (float*)d_out;

    int N = in_sizes[0] / 128;
    int E = in_sizes[1] / 2;
    const int* srcv = ei;
    const int* dstv = ei + E;

    size_t off = 0;
    char* base = (char*)d_ws;
    auto alloc = [&](size_t bytes) -> void* {
        void* p = base + off;
        off = (off + bytes + 255) & ~(size_t)255;
        return p;
    };
    int*    deg  = (int*)alloc((size_t)N * 4);
    int*    cur  = (int*)alloc((size_t)N * 4);
    int*    offs = (int*)alloc((size_t)(N + 1) * 4);
    int*    bsum = (int*)alloc(256 * 4);
    int*    csr  = (int*)alloc((size_t)E * 4);
    float*  as1  = (float*)alloc((size_t)N * 16);
    float*  ad1  = (float*)alloc((size_t)N * 16);
    float*  as2  = (float*)alloc((size_t)N * 4);
    float*  ad2  = (float*)alloc((size_t)N * 4);
    ushort* b1hi = (ushort*)alloc(17 * 4 * 64 * 8 * 2);
    ushort* b1lo = (ushort*)alloc(17 * 4 * 64 * 8 * 2);
    ushort* b2hi = (ushort*)alloc(5 * 8 * 64 * 8 * 2);
    ushort* b2lo = (ushort*)alloc(5 * 8 * 64 * 8 * 2);
    ushort* xhi  = (ushort*)alloc((size_t)N * 128 * 2);   // 12.8 MB
    ushort* xlo  = (ushort*)alloc((size_t)N * 128 * 2);   // 12.8 MB (contiguous after xhi)
    ushort* h1b  = (ushort*)alloc((size_t)N * 256 * 2);   // 25.6 MB packed [node][c][head]
    // aliases: xhi/xlo dead after gemm1 -> h1e (bf16 [N][256]) reuses that slab
    ushort* h1e  = xhi;
    // h1b dead after agg4 -> h2b (bf16 [N][64]) + h2a (f32 [N][64]) reuse it
    ushort* h2b  = h1b;
    float*  h2a  = (float*)(h1b + (size_t)N * 64);

    (void)hipMemsetAsync(deg, 0, (size_t)N * 4, stream);
    (void)hipMemsetAsync(cur, 0, (size_t)N * 4, stream);

    int nbE = (E + 255) / 256;
    hist_k<<<nbE, 256, 0, stream>>>(dstv, E, deg);
    int nbS = (N + 1023) / 1024;
    scan1_k<<<nbS, 1024, 0, stream>>>(deg, offs, bsum, N);
    scan2_k<<<1, 64, 0, stream>>>(bsum, nbS);
    scan3_k<<<nbS, 1024, 0, stream>>>(offs, bsum, N, E);
    fill_k<<<nbE, 256, 0, stream>>>(srcv, dstv, E, offs, cur, csr);

    int n4 = N * 32;
    convx_k<<<(n4 + 255) / 256, 256, 0, stream>>>((const float4*)x, (ushort4*)xhi, (ushort4*)xlo, n4);
    wprep1_k<<<(17 * 4 * 64 * 8 + 255) / 256, 256, 0, stream>>>(W1, aS1, aD1, b1hi, b1lo);
    wprep2_k<<<(5 * 8 * 64 * 8 + 255) / 256, 256, 0, stream>>>(W2, aS2, aD2, b2hi, b2lo);

    int nstrip = (N + 15) / 16;
    int nbG1 = (nstrip + 3) / 4;
    gemm1_mfma_k<<<nbG1, 256, 0, stream>>>(xhi, xlo, (const bf16x8*)b1hi, (const bf16x8*)b1lo,
                                           h1b, as1, ad1, N);

    int nbA = (N * 64 + 255) / 256;
    agg4_k<<<nbA, 256, 0, stream>>>((const ushort4*)h1b, (const float4*)as1, (const float4*)ad1,
                                    offs, csr, b1, h1e, N);

    gemm2_mfma_k<<<nbG1, 256, 0, stream>>>(h1e, (const bf16x8*)b2hi, (const bf16x8*)b2lo,
                                           h2b, as2, ad2, N);

    agg1_k<<<nbA, 256, 0, stream>>>(h2b, as2, ad2, offs, csr, b2, h2a, N);

    int nbGth = (E * 32 + 255) / 256;
    gather_k<<<nbGth, 256, 0, stream>>>((const nfloat4*)h2a, srcv, dstv, (nfloat4*)out, E);
}